// Round 3
// baseline (958.183 us; speedup 1.0000x reference)
//
#include <hip/hip_runtime.h>

typedef __attribute__((ext_vector_type(8))) short short8;
typedef __attribute__((ext_vector_type(4))) float floatx4;
typedef unsigned int u32;

#define CC 256
#define NN 4096
#define NB 8

static __device__ __forceinline__ float b2f(ushort u) {
    union { unsigned int i; float f; } c;
    c.i = ((unsigned int)u) << 16;
    return c.f;
}

static __device__ __forceinline__ ushort f2bf(float f) {
    union { float f; unsigned int u; } c;
    c.f = f;
    unsigned int u = c.u;
    u += 0x7fffu + ((u >> 16) & 1u);
    return (ushort)(u >> 16);
}

static __device__ __forceinline__ short8 load8(const void* p, size_t idx, bool isbf) {
    if (isbf) {
        return *(const short8*)((const ushort*)p + idx);
    } else {
        const float* f = (const float*)p + idx;
        floatx4 a = *(const floatx4*)f;
        floatx4 b = *(const floatx4*)(f + 4);
        short8 r;
        #pragma unroll
        for (int j = 0; j < 4; j++) {
            ((ushort*)&r)[j]     = f2bf(a[j]);
            ((ushort*)&r)[j + 4] = f2bf(b[j]);
        }
        return r;
    }
}

static __device__ __forceinline__ float loadS(const void* p, size_t idx, bool isbf) {
    return isbf ? b2f(((const ushort*)p)[idx]) : ((const float*)p)[idx];
}

static __device__ __forceinline__ bool detect_bf16(const void* x) {
    const ushort* xu = (const ushort*)x;
    int cnt = 0;
    #pragma unroll
    for (int j = 0; j < 8; j++) {
        ushort u = xu[(size_t)j * 1048576];
        int e = (u >> 7) & 0xFF;
        cnt += ((e >= 100 && e <= 141) || (u & 0x7FFF) == 0) ? 1 : 0;
    }
    return cnt >= 7;
}

// -------------------------------------------------------------------------
// proj_mfma: one 64x64 tile of Y = W x_b + bias.  (unchanged)
//   mode 0: K -> ws bf16 [bl][N][C]   mode 1: V -> ws bf16 [bl][C][N]
//   mode 2: P -> d_out fp32 [b][C][N] (direct stores)
// grid (NN/64, CC/64, BC), block 256 (4 waves).
// -------------------------------------------------------------------------
__global__ __launch_bounds__(256) void proj_mfma(
    const void* __restrict__ x, const void* __restrict__ W,
    const void* __restrict__ bias, void* __restrict__ dst, int b0, int mode)
{
    __shared__ __align__(16) ushort A_lds[64 * 40];
    __shared__ __align__(16) ushort Bt_lds[64 * 40];
    __shared__ __align__(16) ushort T_lds[64 * 72];

    const bool isbf = detect_bf16(x);
    const int tid  = threadIdx.x;
    const int wave = tid >> 6;
    const int lane = tid & 63;
    const int l16  = lane & 15;
    const int quad = lane >> 4;

    const int n0 = blockIdx.x * 64;
    const int o0 = blockIdx.y * 64;
    const int bl = blockIdx.z;
    const int b  = b0 + bl;

    floatx4 zero4 = {0.f, 0.f, 0.f, 0.f};
    floatx4 acc[4];
    acc[0] = zero4; acc[1] = zero4; acc[2] = zero4; acc[3] = zero4;

    for (int k0 = 0; k0 < CC; k0 += 32) {
        __syncthreads();
        {   // A = W[o0..+64)[k0..+32)
            int row = tid >> 2, c8 = (tid & 3) * 8;
            *(short8*)&A_lds[row * 40 + c8] =
                load8(W, (size_t)(o0 + row) * CC + k0 + c8, isbf);
        }
        {   // Bt = x[k0..+32)[n0..+64) transposed -> [n][c]
            int c = tid >> 3, n8 = (tid & 7) * 8;
            short8 xv = load8(x, ((size_t)b * CC + k0 + c) * NN + n0 + n8, isbf);
            #pragma unroll
            for (int j = 0; j < 8; j++)
                Bt_lds[(n8 + j) * 40 + c] = ((ushort*)&xv)[j];
        }
        __syncthreads();

        short8 af = *(const short8*)&A_lds[(wave * 16 + l16) * 40 + quad * 8];
        #pragma unroll
        for (int t = 0; t < 4; t++) {
            short8 bf = *(const short8*)&Bt_lds[(t * 16 + l16) * 40 + quad * 8];
            acc[t] = __builtin_amdgcn_mfma_f32_16x16x32_bf16(af, bf, acc[t], 0, 0, 0);
        }
    }

    float biasv[4];
    #pragma unroll
    for (int r = 0; r < 4; r++)
        biasv[r] = loadS(bias, (size_t)(o0 + wave * 16 + quad * 4 + r), isbf);

    if (mode == 2) {
        float* po = (float*)dst;
        #pragma unroll
        for (int t = 0; t < 4; t++)
            #pragma unroll
            for (int r = 0; r < 4; r++)
                po[((size_t)b * CC + o0 + wave * 16 + quad * 4 + r) * NN +
                   n0 + t * 16 + l16] = acc[t][r] + biasv[r];
        return;
    }

    __syncthreads();
    if (mode == 0) {
        #pragma unroll
        for (int t = 0; t < 4; t++)
            #pragma unroll
            for (int r = 0; r < 4; r++)
                T_lds[(t * 16 + l16) * 72 + wave * 16 + quad * 4 + r] =
                    f2bf(acc[t][r] + biasv[r]);
    } else {
        #pragma unroll
        for (int t = 0; t < 4; t++)
            #pragma unroll
            for (int r = 0; r < 4; r++)
                T_lds[(wave * 16 + quad * 4 + r) * 72 + t * 16 + l16] =
                    f2bf(acc[t][r] + biasv[r]);
    }
    __syncthreads();

    ushort* dw = (ushort*)dst;
    if (mode == 0) {
        for (int u = tid; u < 512; u += 256) {
            int n = u >> 3, o8 = (u & 7) * 8;
            *(short8*)&dw[((size_t)bl * NN + n0 + n) * CC + o0 + o8] =
                *(const short8*)&T_lds[n * 72 + o8];
        }
    } else {
        for (int u = tid; u < 512; u += 256) {
            int o = u >> 3, n8 = (u & 7) * 8;
            *(short8*)&dw[((size_t)bl * CC + o0 + o) * NN + n0 + n8] =
                *(const short8*)&T_lds[o * 72 + n8];
        }
    }
}

// -------------------------------------------------------------------------
// attn_mfma v4: QBLK=64, 4 waves, KVBLK=32, 59392 B LDS (proven 2 blocks/CU),
// register-prefetch software pipeline (tile it+1 loads in flight under tile
// it compute), pad-based conflict-free LDS layouts (K rows 264, V rows 36,
// P rows 40), wave-local P fence. grid (NN/64, BC), block 256.
// -------------------------------------------------------------------------
__global__ __launch_bounds__(256, 2) void attn_mfma(
    const void* __restrict__ x,
    const void* __restrict__ Wq, const void* __restrict__ bq,
    const ushort* __restrict__ k_ws, const ushort* __restrict__ v_ws,
    float* __restrict__ out, int b0)
{
    // Pool: 29696 ushorts = 59392 B  (v1's footprint -> 2 blocks/CU)
    __shared__ __align__(16) ushort lds[29696];
    // Flash phase:
    ushort* K_lds  = lds;            // [32][264]  16B-slot reads 2-way free
    ushort* Vt_lds = lds + 8448;     // [256][36]
    ushort* P_lds  = lds + 17664;    // [64][40]   wave-local rows
    // Phase A aliases:
    ushort* Qt_lds = lds;            // [64][264]
    ushort* Wc_lds = lds + 16896;    // [256][40]
    ushort* Xt_lds = lds + 27136;    // [64][40]
    float*  Tf     = (float*)lds;    // [128][68] fp32 epilogue

    const bool isbf = detect_bf16(x);
    const int tid  = threadIdx.x;
    const int wave = tid >> 6;
    const int lane = tid & 63;
    const int l16  = lane & 15;
    const int quad = lane >> 4;
    const int bl = blockIdx.y;
    const int b  = b0 + bl;
    const int n0 = blockIdx.x * 64;

    floatx4 zero4 = {0.f, 0.f, 0.f, 0.f};

    // ---- Phase A: Q = (x^T Wq^T + bq) * C^-0.5, D[n][o] ----
    {
        floatx4 qacc[16];
        #pragma unroll
        for (int t = 0; t < 16; t++) qacc[t] = zero4;

        for (int k0 = 0; k0 < CC; k0 += 32) {
            __syncthreads();
            #pragma unroll
            for (int i = 0; i < 4; i++) {
                int u = tid + i * 256;
                int row = u >> 2, c8 = (u & 3) * 8;
                *(short8*)&Wc_lds[row * 40 + c8] =
                    load8(Wq, (size_t)row * CC + k0 + c8, isbf);
            }
            {
                int c = tid >> 3, n8 = (tid & 7) * 8;
                short8 xv = load8(x, ((size_t)b * CC + k0 + c) * NN + n0 + n8, isbf);
                #pragma unroll
                for (int j = 0; j < 8; j++)
                    Xt_lds[(n8 + j) * 40 + c] = ((ushort*)&xv)[j];
            }
            __syncthreads();

            short8 af = *(const short8*)&Xt_lds[(wave * 16 + l16) * 40 + quad * 8];
            #pragma unroll
            for (int ct = 0; ct < 16; ct++) {
                short8 bf = *(const short8*)&Wc_lds[(ct * 16 + l16) * 40 + quad * 8];
                qacc[ct] = __builtin_amdgcn_mfma_f32_16x16x32_bf16(af, bf, qacc[ct], 0, 0, 0);
            }
        }

        __syncthreads();
        #pragma unroll
        for (int ct = 0; ct < 16; ct++) {
            float bqv = loadS(bq, (size_t)(ct * 16 + l16), isbf);
            #pragma unroll
            for (int r = 0; r < 4; r++)
                Qt_lds[(wave * 16 + quad * 4 + r) * 264 + ct * 16 + l16] =
                    f2bf((qacc[ct][r] + bqv) * 0.0625f);
        }
    }
    __syncthreads();   // Qt ushort writes -> short8 reads
    short8 qf[8];
    #pragma unroll
    for (int s = 0; s < 8; s++)
        qf[s] = *(const short8*)&Qt_lds[(wave * 16 + l16) * 264 + s * 32 + quad * 8];
    __syncthreads();   // all waves done with Qt before staging overwrites it

    // ---- Phase B: flash attention, KVBLK=32, reg-prefetch pipeline ----
    const ushort* kp = k_ws + (size_t)bl * NN * CC;   // [n][C]
    const ushort* vp = v_ws + (size_t)bl * CC * NN;   // [C][n]

    floatx4 Oacc[16];
    #pragma unroll
    for (int t = 0; t < 16; t++) Oacc[t] = zero4;
    float mrow[4], lrow[4];
    #pragma unroll
    for (int r = 0; r < 4; r++) { mrow[r] = -1e30f; lrow[r] = 0.f; }

    const int krow  = wave * 8 + (lane >> 3);     // K stage row (this lane)
    const int kslot = lane & 7;                    // K stage slot base
    const int vchb  = wave * 64 + (lane >> 2);    // V stage channel base
    const int vslot = lane & 3;                    // V stage slot

    auto loadT = [&](int it, short8* kn, short8* vn) {
        int m0 = it * 32;
        #pragma unroll
        for (int i = 0; i < 4; i++)
            kn[i] = *(const short8*)&kp[(size_t)(m0 + krow) * CC + (kslot + i * 8) * 8];
        #pragma unroll
        for (int i = 0; i < 4; i++)
            vn[i] = *(const short8*)&vp[(size_t)(vchb + i * 16) * NN + m0 + vslot * 8];
    };

    auto flash_step = [&](int it, short8* kw, short8* vw, short8* kn, short8* vn) {
        __syncthreads();                   // all waves done reading prev tile
        #pragma unroll
        for (int i = 0; i < 4; i++)        // compiler waits vmcnt for kw here
            *(short8*)&K_lds[krow * 264 + (kslot + i * 8) * 8] = kw[i];
        #pragma unroll
        for (int i = 0; i < 4; i++)
            *(short8*)&Vt_lds[(vchb + i * 16) * 36 + vslot * 8] = vw[i];
        if (it + 1 < NN / 32) loadT(it + 1, kn, vn);   // async, lands under compute
        __syncthreads();                   // tile visible

        // QK^T: S[t] = Q . K(16 keys of t), k=256 over 8 slices
        floatx4 S[2];
        S[0] = zero4; S[1] = zero4;
        #pragma unroll
        for (int t = 0; t < 2; t++) {
            int row = t * 16 + l16;
            #pragma unroll
            for (int s = 0; s < 8; s++) {
                short8 kf = *(const short8*)&K_lds[row * 264 + (s * 4 + quad) * 8];
                S[t] = __builtin_amdgcn_mfma_f32_16x16x32_bf16(qf[s], kf, S[t], 0, 0, 0);
            }
        }

        // online softmax: rows = quad*4+r, keys = (t*16+l16)
        float alpha[4];
        #pragma unroll
        for (int r = 0; r < 4; r++) {
            float mx = fmaxf(S[0][r], S[1][r]);
            mx = fmaxf(mx, __shfl_xor(mx, 1, 64));
            mx = fmaxf(mx, __shfl_xor(mx, 2, 64));
            mx = fmaxf(mx, __shfl_xor(mx, 4, 64));
            mx = fmaxf(mx, __shfl_xor(mx, 8, 64));
            float mn = fmaxf(mrow[r], mx);
            float al = __expf(mrow[r] - mn);
            mrow[r] = mn;
            float p0 = __expf(S[0][r] - mn);
            float p1 = __expf(S[1][r] - mn);
            S[0][r] = p0; S[1][r] = p1;
            float rs = p0 + p1;
            rs += __shfl_xor(rs, 1, 64);
            rs += __shfl_xor(rs, 2, 64);
            rs += __shfl_xor(rs, 4, 64);
            rs += __shfl_xor(rs, 8, 64);
            lrow[r] = lrow[r] * al + rs;
            alpha[r] = al;
        }

        // write P (wave-local rows), cols = key index
        #pragma unroll
        for (int r = 0; r < 4; r++) {
            int row = wave * 16 + quad * 4 + r;
            P_lds[row * 40 + l16]      = f2bf(S[0][r]);
            P_lds[row * 40 + 16 + l16] = f2bf(S[1][r]);
        }

        // rescale O while P writes drain (VALU overlaps DS pipe)
        #pragma unroll
        for (int ct = 0; ct < 16; ct++)
            #pragma unroll
            for (int r = 0; r < 4; r++)
                Oacc[ct][r] *= alpha[r];

        // in-wave fence (DS in-order per wave); pin scheduler (rule 18)
        asm volatile("s_waitcnt lgkmcnt(0)" ::: "memory");
        __builtin_amdgcn_sched_barrier(0);

        // PV: O[ct] += P . V(16 ch of ct), one MFMA per ct (k=32)
        int prow = wave * 16 + l16;
        short8 pf = *(const short8*)&P_lds[prow * 40 + quad * 8];
        #pragma unroll
        for (int ct = 0; ct < 16; ct++) {
            int ch = ct * 16 + l16;
            short8 vf = *(const short8*)&Vt_lds[ch * 36 + quad * 8];
            Oacc[ct] = __builtin_amdgcn_mfma_f32_16x16x32_bf16(pf, vf, Oacc[ct], 0, 0, 0);
        }
    };

    short8 kA[4], vA[4], kB[4], vB[4];
    loadT(0, kA, vA);
    #pragma unroll 1
    for (int it = 0; it < NN / 32; it += 2) {
        flash_step(it,     kA, vA, kB, vB);
        flash_step(it + 1, kB, vB, kA, vA);
    }

    // ---- epilogue: out = h/l + P (fp32 RMW), two 128-channel halves ----
    float linv[4];
    #pragma unroll
    for (int r = 0; r < 4; r++) linv[r] = 1.0f / lrow[r];

    #pragma unroll
    for (int h = 0; h < 2; h++) {
        __syncthreads();   // flash LDS dead (or prev half consumed)
        #pragma unroll
        for (int ct = h * 8; ct < h * 8 + 8; ct++)
            #pragma unroll
            for (int r = 0; r < 4; r++)
                Tf[(ct * 16 + l16 - h * 128) * 68 + wave * 16 + quad * 4 + r] =
                    Oacc[ct][r] * linv[r];
        __syncthreads();
        #pragma unroll
        for (int i = 0; i < 8; i++) {
            int u = tid + i * 256;           // 2048 float4 slots = 128ch x 16
            int row = u >> 4, col4 = (u & 15) * 4;
            size_t gi = ((size_t)b * CC + h * 128 + row) * NN + n0 + col4;
            floatx4 pv = *(const floatx4*)&out[gi];
            floatx4 tv = *(const floatx4*)&Tf[row * 68 + col4];
            pv[0] += tv[0]; pv[1] += tv[1]; pv[2] += tv[2]; pv[3] += tv[3];
            *(floatx4*)&out[gi] = pv;
        }
    }
}

// -------------------------------------------------------------------------
extern "C" void kernel_launch(void* const* d_in, const int* in_sizes, int n_in,
                              void* d_out, int out_size, void* d_ws, size_t ws_size,
                              hipStream_t stream) {
    int xi = 0;
    for (int i = 0; i < n_in; i++)
        if (in_sizes[i] == NB * CC * NN) xi = i;

    const void *x, *Wq, *bq, *Wk, *bk, *Wv, *bv, *Wp, *bp;
    if (xi == 0) {
        x  = d_in[0];
        Wq = d_in[1]; bq = d_in[2];
        Wk = d_in[3]; bk = d_in[4];
        Wv = d_in[5]; bv = d_in[6];
        Wp = d_in[7]; bp = d_in[8];
    } else {
        int wi[4], bi[4], nw = 0, nb = 0;
        for (int i = 0; i < n_in; i++) {
            if (i == xi) continue;
            if (in_sizes[i] == CC * CC) { if (nw < 4) wi[nw++] = i; }
            else                        { if (nb < 4) bi[nb++] = i; }
        }
        x  = d_in[xi];
        Wk = d_in[wi[0]]; Wp = d_in[wi[1]]; Wq = d_in[wi[2]]; Wv = d_in[wi[3]];
        bk = d_in[bi[0]]; bp = d_in[bi[1]]; bq = d_in[bi[2]]; bv = d_in[bi[3]];
    }

    float*  out = (float*)d_out;     // fp32 output
    ushort* ws  = (ushort*)d_ws;

    const size_t tsz_b = (size_t)NN * CC;
    int BC = 8;
    while (BC > 1 && (size_t)BC * tsz_b * 2 * 2 > ws_size) BC >>= 1;
    ushort* k_ws = ws;
    ushort* v_ws = ws + (size_t)BC * tsz_b;

    // P (fp32) for all batches -> d_out
    proj_mfma<<<dim3(NN / 64, CC / 64, NB), dim3(256), 0, stream>>>(
        x, Wp, bp, (void*)out, 0, 2);

    for (int c0 = 0; c0 < NB; c0 += BC) {
        proj_mfma<<<dim3(NN / 64, CC / 64, BC), dim3(256), 0, stream>>>(
            x, Wk, bk, (void*)k_ws, c0, 0);
        proj_mfma<<<dim3(NN / 64, CC / 64, BC), dim3(256), 0, stream>>>(
            x, Wv, bv, (void*)v_ws, c0, 1);
        attn_mfma<<<dim3(NN / 64, BC), dim3(256), 0, stream>>>(
            x, Wq, bq, k_ws, v_ws, out, c0);
    }
}

// Round 4
// 499.866 us; speedup vs baseline: 1.9169x; 1.9169x over previous
//
#include <hip/hip_runtime.h>

typedef __attribute__((ext_vector_type(8))) short short8;
typedef __attribute__((ext_vector_type(4))) float floatx4;
typedef unsigned int u32;

#define CC 256
#define NN 4096
#define NB 8

static __device__ __forceinline__ float b2f(ushort u) {
    union { unsigned int i; float f; } c;
    c.i = ((unsigned int)u) << 16;
    return c.f;
}

static __device__ __forceinline__ ushort f2bf(float f) {
    union { float f; unsigned int u; } c;
    c.f = f;
    unsigned int u = c.u;
    u += 0x7fffu + ((u >> 16) & 1u);
    return (ushort)(u >> 16);
}

static __device__ __forceinline__ short8 load8(const void* p, size_t idx, bool isbf) {
    if (isbf) {
        return *(const short8*)((const ushort*)p + idx);
    } else {
        const float* f = (const float*)p + idx;
        floatx4 a = *(const floatx4*)f;
        floatx4 b = *(const floatx4*)(f + 4);
        short8 r;
        #pragma unroll
        for (int j = 0; j < 4; j++) {
            ((ushort*)&r)[j]     = f2bf(a[j]);
            ((ushort*)&r)[j + 4] = f2bf(b[j]);
        }
        return r;
    }
}

static __device__ __forceinline__ float loadS(const void* p, size_t idx, bool isbf) {
    return isbf ? b2f(((const ushort*)p)[idx]) : ((const float*)p)[idx];
}

static __device__ __forceinline__ bool detect_bf16(const void* x) {
    const ushort* xu = (const ushort*)x;
    int cnt = 0;
    #pragma unroll
    for (int j = 0; j < 8; j++) {
        ushort u = xu[(size_t)j * 1048576];
        int e = (u >> 7) & 0xFF;
        cnt += ((e >= 100 && e <= 141) || (u & 0x7FFF) == 0) ? 1 : 0;
    }
    return cnt >= 7;
}

// async global -> LDS, 16B per lane; LDS dest is wave-uniform base (+lane*16B)
static __device__ __forceinline__ void gll16(const ushort* g, ushort* l) {
    __builtin_amdgcn_global_load_lds(
        (const __attribute__((address_space(1))) u32*)g,
        (__attribute__((address_space(3))) u32*)l, 16, 0, 0);
}

// -------------------------------------------------------------------------
// proj_mfma: one 64x64 tile of Y = W x_b + bias.  (unchanged)
//   mode 0: K -> ws bf16 [bl][N][C]   mode 1: V -> ws bf16 [bl][C][N]
//   mode 2: P -> d_out fp32 [b][C][N] (direct stores)
// grid (NN/64, CC/64, BC), block 256 (4 waves).
// -------------------------------------------------------------------------
__global__ __launch_bounds__(256) void proj_mfma(
    const void* __restrict__ x, const void* __restrict__ W,
    const void* __restrict__ bias, void* __restrict__ dst, int b0, int mode)
{
    __shared__ __align__(16) ushort A_lds[64 * 40];
    __shared__ __align__(16) ushort Bt_lds[64 * 40];
    __shared__ __align__(16) ushort T_lds[64 * 72];

    const bool isbf = detect_bf16(x);
    const int tid  = threadIdx.x;
    const int wave = tid >> 6;
    const int lane = tid & 63;
    const int l16  = lane & 15;
    const int quad = lane >> 4;

    const int n0 = blockIdx.x * 64;
    const int o0 = blockIdx.y * 64;
    const int bl = blockIdx.z;
    const int b  = b0 + bl;

    floatx4 zero4 = {0.f, 0.f, 0.f, 0.f};
    floatx4 acc[4];
    acc[0] = zero4; acc[1] = zero4; acc[2] = zero4; acc[3] = zero4;

    for (int k0 = 0; k0 < CC; k0 += 32) {
        __syncthreads();
        {   // A = W[o0..+64)[k0..+32)
            int row = tid >> 2, c8 = (tid & 3) * 8;
            *(short8*)&A_lds[row * 40 + c8] =
                load8(W, (size_t)(o0 + row) * CC + k0 + c8, isbf);
        }
        {   // Bt = x[k0..+32)[n0..+64) transposed -> [n][c]
            int c = tid >> 3, n8 = (tid & 7) * 8;
            short8 xv = load8(x, ((size_t)b * CC + k0 + c) * NN + n0 + n8, isbf);
            #pragma unroll
            for (int j = 0; j < 8; j++)
                Bt_lds[(n8 + j) * 40 + c] = ((ushort*)&xv)[j];
        }
        __syncthreads();

        short8 af = *(const short8*)&A_lds[(wave * 16 + l16) * 40 + quad * 8];
        #pragma unroll
        for (int t = 0; t < 4; t++) {
            short8 bf = *(const short8*)&Bt_lds[(t * 16 + l16) * 40 + quad * 8];
            acc[t] = __builtin_amdgcn_mfma_f32_16x16x32_bf16(af, bf, acc[t], 0, 0, 0);
        }
    }

    float biasv[4];
    #pragma unroll
    for (int r = 0; r < 4; r++)
        biasv[r] = loadS(bias, (size_t)(o0 + wave * 16 + quad * 4 + r), isbf);

    if (mode == 2) {
        float* po = (float*)dst;
        #pragma unroll
        for (int t = 0; t < 4; t++)
            #pragma unroll
            for (int r = 0; r < 4; r++)
                po[((size_t)b * CC + o0 + wave * 16 + quad * 4 + r) * NN +
                   n0 + t * 16 + l16] = acc[t][r] + biasv[r];
        return;
    }

    __syncthreads();
    if (mode == 0) {
        #pragma unroll
        for (int t = 0; t < 4; t++)
            #pragma unroll
            for (int r = 0; r < 4; r++)
                T_lds[(t * 16 + l16) * 72 + wave * 16 + quad * 4 + r] =
                    f2bf(acc[t][r] + biasv[r]);
    } else {
        #pragma unroll
        for (int t = 0; t < 4; t++)
            #pragma unroll
            for (int r = 0; r < 4; r++)
                T_lds[(wave * 16 + quad * 4 + r) * 72 + t * 16 + l16] =
                    f2bf(acc[t][r] + biasv[r]);
    }
    __syncthreads();

    ushort* dw = (ushort*)dst;
    if (mode == 0) {
        for (int u = tid; u < 512; u += 256) {
            int n = u >> 3, o8 = (u & 7) * 8;
            *(short8*)&dw[((size_t)bl * NN + n0 + n) * CC + o0 + o8] =
                *(const short8*)&T_lds[n * 72 + o8];
        }
    } else {
        for (int u = tid; u < 512; u += 256) {
            int o = u >> 3, n8 = (u & 7) * 8;
            *(short8*)&dw[((size_t)bl * CC + o0 + o) * NN + n0 + n8] =
                *(const short8*)&T_lds[o * 72 + n8];
        }
    }
}

// -------------------------------------------------------------------------
// attn_mfma v5: v1 structure (KVBLK=32, 59392 B LDS -> 2 blocks/CU proven)
// + global_load_lds staging (XOR-swizzled K source/read, linear V) replacing
// v1's VALU staging, + wave-local P fence (2 barriers/iter vs v1's 3).
// No loads in flight across barriers (v4 lesson: __syncthreads drains vmcnt).
// grid (NN/64, BC), block 256 (4 waves).
// -------------------------------------------------------------------------
__global__ __launch_bounds__(256, 2) void attn_mfma(
    const void* __restrict__ x,
    const void* __restrict__ Wq, const void* __restrict__ bq,
    const ushort* __restrict__ k_ws, const ushort* __restrict__ v_ws,
    float* __restrict__ out, int b0)
{
    // Pool: 29696 ushorts = 59392 B  (v1's footprint -> 2 blocks/CU)
    __shared__ __align__(16) ushort lds[29696];
    // Flash phase:
    ushort* K_lds  = lds;            // [32][256] swizzled: slot p holds p^(row&7)
    ushort* Vt_lds = lds + 8192;     // [256][32] linear (64B rows, reads conflict-free)
    ushort* P_lds  = lds + 16384;    // [4][16][40] wave-local
    // Phase A aliases:
    ushort* Qt_lds = lds;            // [64][264]
    ushort* Wc_lds = lds + 16896;    // [256][40]
    ushort* Xt_lds = lds + 27136;    // [64][40]
    float*  Tf     = (float*)lds;    // [128][68] fp32 epilogue

    const bool isbf = detect_bf16(x);
    const int tid  = threadIdx.x;
    const int wave = tid >> 6;
    const int lane = tid & 63;
    const int l16  = lane & 15;
    const int quad = lane >> 4;
    const int bl = blockIdx.y;
    const int b  = b0 + bl;
    const int n0 = blockIdx.x * 64;

    floatx4 zero4 = {0.f, 0.f, 0.f, 0.f};

    // ---- Phase A: Q = (x^T Wq^T + bq) * C^-0.5, D[n][o]  (v1 verbatim) ----
    {
        floatx4 qacc[16];
        #pragma unroll
        for (int t = 0; t < 16; t++) qacc[t] = zero4;

        for (int k0 = 0; k0 < CC; k0 += 32) {
            __syncthreads();
            #pragma unroll
            for (int i = 0; i < 4; i++) {
                int u = tid + i * 256;
                int row = u >> 2, c8 = (u & 3) * 8;
                *(short8*)&Wc_lds[row * 40 + c8] =
                    load8(Wq, (size_t)row * CC + k0 + c8, isbf);
            }
            {
                int c = tid >> 3, n8 = (tid & 7) * 8;
                short8 xv = load8(x, ((size_t)b * CC + k0 + c) * NN + n0 + n8, isbf);
                #pragma unroll
                for (int j = 0; j < 8; j++)
                    Xt_lds[(n8 + j) * 40 + c] = ((ushort*)&xv)[j];
            }
            __syncthreads();

            short8 af = *(const short8*)&Xt_lds[(wave * 16 + l16) * 40 + quad * 8];
            #pragma unroll
            for (int ct = 0; ct < 16; ct++) {
                short8 bf = *(const short8*)&Wc_lds[(ct * 16 + l16) * 40 + quad * 8];
                qacc[ct] = __builtin_amdgcn_mfma_f32_16x16x32_bf16(af, bf, qacc[ct], 0, 0, 0);
            }
        }

        __syncthreads();
        #pragma unroll
        for (int ct = 0; ct < 16; ct++) {
            float bqv = loadS(bq, (size_t)(ct * 16 + l16), isbf);
            #pragma unroll
            for (int r = 0; r < 4; r++)
                Qt_lds[(wave * 16 + quad * 4 + r) * 264 + ct * 16 + l16] =
                    f2bf((qacc[ct][r] + bqv) * 0.0625f);
        }
    }
    __syncthreads();   // Qt ushort writes -> short8 reads
    short8 qf[8];
    #pragma unroll
    for (int s = 0; s < 8; s++)
        qf[s] = *(const short8*)&Qt_lds[(wave * 16 + l16) * 264 + s * 32 + quad * 8];
    __syncthreads();   // all waves done with Qt before staging overwrites it

    // ---- Phase B: flash attention, KVBLK=32, gll staging ----
    const ushort* kp = k_ws + (size_t)bl * NN * CC;   // [n][C]
    const ushort* vp = v_ws + (size_t)bl * CC * NN;   // [C][n]

    floatx4 Oacc[16];
    #pragma unroll
    for (int t = 0; t < 16; t++) Oacc[t] = zero4;
    float mrow[4], lrow[4];
    #pragma unroll
    for (int r = 0; r < 4; r++) { mrow[r] = -1e30f; lrow[r] = 0.f; }

    #pragma unroll 1
    for (int it = 0; it < NN / 32; ++it) {
        const int m0 = it * 32;
        __syncthreads();   // prev tile reads done (nothing outstanding: cheap)

        // stage K (16 x 1KB chunks) + V (16 x 1KB chunks), 8 per wave.
        // K: LDS linear dest; source pre-swizzled so LDS slot p of row r
        // holds global 16B-block (p ^ (r&7)).  V: fully linear.
        #pragma unroll
        for (int i = 0; i < 4; i++) {
            int c = wave * 4 + i;
            {   // K chunk: 2 rows of 512 B
                int row = c * 2 + (lane >> 5);
                int sw  = (lane & 31) ^ (row & 7);
                gll16(kp + (size_t)(m0 + row) * CC + sw * 8, K_lds + c * 512);
            }
            {   // V chunk: 16 channel-rows of 64 B
                int ch = c * 16 + (lane >> 2);
                gll16(vp + (size_t)ch * NN + m0 + (lane & 3) * 8, Vt_lds + c * 512);
            }
        }
        __syncthreads();   // vmcnt(0) drained here: tile visible (intended)

        // QK^T: S[t] = Q . K(16 keys of t), k=256 over 8 slices
        floatx4 S[2];
        S[0] = zero4; S[1] = zero4;
        #pragma unroll
        for (int t = 0; t < 2; t++) {
            int row = t * 16 + l16;
            int rsw = row & 7;
            #pragma unroll
            for (int s = 0; s < 8; s++) {
                short8 kf = *(const short8*)&K_lds[row * 256 + ((s * 4 + quad) ^ rsw) * 8];
                S[t] = __builtin_amdgcn_mfma_f32_16x16x32_bf16(qf[s], kf, S[t], 0, 0, 0);
            }
        }

        // online softmax: rows = quad*4+r, keys = (t*16+l16)
        float alpha[4];
        #pragma unroll
        for (int r = 0; r < 4; r++) {
            float mx = fmaxf(S[0][r], S[1][r]);
            mx = fmaxf(mx, __shfl_xor(mx, 1, 64));
            mx = fmaxf(mx, __shfl_xor(mx, 2, 64));
            mx = fmaxf(mx, __shfl_xor(mx, 4, 64));
            mx = fmaxf(mx, __shfl_xor(mx, 8, 64));
            float mn = fmaxf(mrow[r], mx);
            float al = __expf(mrow[r] - mn);
            mrow[r] = mn;
            float p0 = __expf(S[0][r] - mn);
            float p1 = __expf(S[1][r] - mn);
            S[0][r] = p0; S[1][r] = p1;
            float rs = p0 + p1;
            rs += __shfl_xor(rs, 1, 64);
            rs += __shfl_xor(rs, 2, 64);
            rs += __shfl_xor(rs, 4, 64);
            rs += __shfl_xor(rs, 8, 64);
            lrow[r] = lrow[r] * al + rs;
            alpha[r] = al;
        }

        // write P (wave-local rows; only this wave reads them back)
        #pragma unroll
        for (int r = 0; r < 4; r++) {
            int row = wave * 640 + (quad * 4 + r) * 40;
            P_lds[row + l16]      = f2bf(S[0][r]);
            P_lds[row + 16 + l16] = f2bf(S[1][r]);
        }

        // rescale O while P writes drain (VALU overlaps DS pipe)
        #pragma unroll
        for (int ct = 0; ct < 16; ct++)
            #pragma unroll
            for (int r = 0; r < 4; r++)
                Oacc[ct][r] *= alpha[r];

        // in-wave fence (DS in-order per wave); pin scheduler (rule 18)
        asm volatile("s_waitcnt lgkmcnt(0)" ::: "memory");
        __builtin_amdgcn_sched_barrier(0);

        // PV: O[ct] += P . V(16 ch of ct), one MFMA per ct (k=32)
        short8 pf = *(const short8*)&P_lds[wave * 640 + l16 * 40 + quad * 8];
        #pragma unroll
        for (int ct = 0; ct < 16; ct++) {
            int ch = ct * 16 + l16;
            short8 vf = *(const short8*)&Vt_lds[ch * 32 + quad * 8];
            Oacc[ct] = __builtin_amdgcn_mfma_f32_16x16x32_bf16(pf, vf, Oacc[ct], 0, 0, 0);
        }
    }

    // ---- epilogue: out = h/l + P (fp32 RMW), two 128-channel halves ----
    float linv[4];
    #pragma unroll
    for (int r = 0; r < 4; r++) linv[r] = 1.0f / lrow[r];

    #pragma unroll
    for (int h = 0; h < 2; h++) {
        __syncthreads();   // flash LDS dead (or prev half consumed)
        #pragma unroll
        for (int ct = h * 8; ct < h * 8 + 8; ct++)
            #pragma unroll
            for (int r = 0; r < 4; r++)
                Tf[(ct * 16 + l16 - h * 128) * 68 + wave * 16 + quad * 4 + r] =
                    Oacc[ct][r] * linv[r];
        __syncthreads();
        #pragma unroll
        for (int i = 0; i < 8; i++) {
            int u = tid + i * 256;           // 2048 float4 slots = 128ch x 16
            int row = u >> 4, col4 = (u & 15) * 4;
            size_t gi = ((size_t)b * CC + h * 128 + row) * NN + n0 + col4;
            floatx4 pv = *(const floatx4*)&out[gi];
            floatx4 tv = *(const floatx4*)&Tf[row * 68 + col4];
            pv[0] += tv[0]; pv[1] += tv[1]; pv[2] += tv[2]; pv[3] += tv[3];
            *(floatx4*)&out[gi] = pv;
        }
    }
}

// -------------------------------------------------------------------------
extern "C" void kernel_launch(void* const* d_in, const int* in_sizes, int n_in,
                              void* d_out, int out_size, void* d_ws, size_t ws_size,
                              hipStream_t stream) {
    int xi = 0;
    for (int i = 0; i < n_in; i++)
        if (in_sizes[i] == NB * CC * NN) xi = i;

    const void *x, *Wq, *bq, *Wk, *bk, *Wv, *bv, *Wp, *bp;
    if (xi == 0) {
        x  = d_in[0];
        Wq = d_in[1]; bq = d_in[2];
        Wk = d_in[3]; bk = d_in[4];
        Wv = d_in[5]; bv = d_in[6];
        Wp = d_in[7]; bp = d_in[8];
    } else {
        int wi[4], bi[4], nw = 0, nb = 0;
        for (int i = 0; i < n_in; i++) {
            if (i == xi) continue;
            if (in_sizes[i] == CC * CC) { if (nw < 4) wi[nw++] = i; }
            else                        { if (nb < 4) bi[nb++] = i; }
        }
        x  = d_in[xi];
        Wk = d_in[wi[0]]; Wp = d_in[wi[1]]; Wq = d_in[wi[2]]; Wv = d_in[wi[3]];
        bk = d_in[bi[0]]; bp = d_in[bi[1]]; bq = d_in[bi[2]]; bv = d_in[bi[3]];
    }

    float*  out = (float*)d_out;     // fp32 output
    ushort* ws  = (ushort*)d_ws;

    const size_t tsz_b = (size_t)NN * CC;
    int BC = 8;
    while (BC > 1 && (size_t)BC * tsz_b * 2 * 2 > ws_size) BC >>= 1;
    ushort* k_ws = ws;
    ushort* v_ws = ws + (size_t)BC * tsz_b;

    // P (fp32) for all batches -> d_out
    proj_mfma<<<dim3(NN / 64, CC / 64, NB), dim3(256), 0, stream>>>(
        x, Wp, bp, (void*)out, 0, 2);

    for (int c0 = 0; c0 < NB; c0 += BC) {
        proj_mfma<<<dim3(NN / 64, CC / 64, BC), dim3(256), 0, stream>>>(
            x, Wk, bk, (void*)k_ws, c0, 0);
        proj_mfma<<<dim3(NN / 64, CC / 64, BC), dim3(256), 0, stream>>>(
            x, Wv, bv, (void*)v_ws, c0, 1);
        attn_mfma<<<dim3(NN / 64, BC), dim3(256), 0, stream>>>(
            x, Wq, bq, k_ws, v_ws, out, c0);
    }
}

// Round 6
// 468.256 us; speedup vs baseline: 2.0463x; 1.0675x over previous
//
#include <hip/hip_runtime.h>

typedef __attribute__((ext_vector_type(8))) short short8;
typedef __attribute__((ext_vector_type(4))) float floatx4;
typedef unsigned int u32;

#define CC 256
#define NN 4096
#define NB 8

static __device__ __forceinline__ float b2f(ushort u) {
    union { unsigned int i; float f; } c;
    c.i = ((unsigned int)u) << 16;
    return c.f;
}

static __device__ __forceinline__ ushort f2bf(float f) {
    union { float f; unsigned int u; } c;
    c.f = f;
    unsigned int u = c.u;
    u += 0x7fffu + ((u >> 16) & 1u);
    return (ushort)(u >> 16);
}

static __device__ __forceinline__ short8 load8(const void* p, size_t idx, bool isbf) {
    if (isbf) {
        return *(const short8*)((const ushort*)p + idx);
    } else {
        const float* f = (const float*)p + idx;
        floatx4 a = *(const floatx4*)f;
        floatx4 b = *(const floatx4*)(f + 4);
        short8 r;
        #pragma unroll
        for (int j = 0; j < 4; j++) {
            ((ushort*)&r)[j]     = f2bf(a[j]);
            ((ushort*)&r)[j + 4] = f2bf(b[j]);
        }
        return r;
    }
}

static __device__ __forceinline__ float loadS(const void* p, size_t idx, bool isbf) {
    return isbf ? b2f(((const ushort*)p)[idx]) : ((const float*)p)[idx];
}

static __device__ __forceinline__ bool detect_bf16(const void* x) {
    const ushort* xu = (const ushort*)x;
    int cnt = 0;
    #pragma unroll
    for (int j = 0; j < 8; j++) {
        ushort u = xu[(size_t)j * 1048576];
        int e = (u >> 7) & 0xFF;
        cnt += ((e >= 100 && e <= 141) || (u & 0x7FFF) == 0) ? 1 : 0;
    }
    return cnt >= 7;
}

// async global -> LDS, 16B per lane; LDS dest is wave-uniform base (+lane*16B)
static __device__ __forceinline__ void gll16(const ushort* g, ushort* l) {
    __builtin_amdgcn_global_load_lds(
        (const __attribute__((address_space(1))) u32*)g,
        (__attribute__((address_space(3))) u32*)l, 16, 0, 0);
}

// -------------------------------------------------------------------------
// projkvp: one 64x64 tile of K, V, AND P from a single x staging pass.
//   K -> k_ws bf16 [bl][N][C];  V -> v_ws bf16 [bl][C][N];
//   P -> out fp32 [b][C][N] (direct stores).
// grid (NN/64, CC/64, BC), block 256 (4 waves). LDS 29696 B.
// -------------------------------------------------------------------------
__global__ __launch_bounds__(256) void projkvp(
    const void* __restrict__ x,
    const void* __restrict__ Wk, const void* __restrict__ bk,
    const void* __restrict__ Wv, const void* __restrict__ bv,
    const void* __restrict__ Wp, const void* __restrict__ bp,
    ushort* __restrict__ k_ws, ushort* __restrict__ v_ws,
    float* __restrict__ out, int b0)
{
    __shared__ __align__(16) ushort A_lds[3][64 * 40];
    __shared__ __align__(16) ushort Bt_lds[64 * 40];
    __shared__ __align__(16) ushort T_lds[64 * 72];

    const bool isbf = detect_bf16(x);
    const int tid  = threadIdx.x;
    const int wave = tid >> 6;
    const int lane = tid & 63;
    const int l16  = lane & 15;
    const int quad = lane >> 4;

    const int n0 = blockIdx.x * 64;
    const int o0 = blockIdx.y * 64;
    const int bl = blockIdx.z;
    const int b  = b0 + bl;

    floatx4 zero4 = {0.f, 0.f, 0.f, 0.f};
    floatx4 acc[3][4];
    #pragma unroll
    for (int w = 0; w < 3; w++)
        #pragma unroll
        for (int t = 0; t < 4; t++) acc[w][t] = zero4;

    const void* Ws[3] = {Wk, Wv, Wp};

    for (int k0 = 0; k0 < CC; k0 += 32) {
        __syncthreads();
        {   // A[w] = W_w[o0..+64)[k0..+32)
            int row = tid >> 2, c8 = (tid & 3) * 8;
            #pragma unroll
            for (int w = 0; w < 3; w++)
                *(short8*)&A_lds[w][row * 40 + c8] =
                    load8(Ws[w], (size_t)(o0 + row) * CC + k0 + c8, isbf);
        }
        {   // Bt = x[k0..+32)[n0..+64) transposed -> [n][c]
            int c = tid >> 3, n8 = (tid & 7) * 8;
            short8 xv = load8(x, ((size_t)b * CC + k0 + c) * NN + n0 + n8, isbf);
            #pragma unroll
            for (int j = 0; j < 8; j++)
                Bt_lds[(n8 + j) * 40 + c] = ((ushort*)&xv)[j];
        }
        __syncthreads();

        short8 af[3];
        #pragma unroll
        for (int w = 0; w < 3; w++)
            af[w] = *(const short8*)&A_lds[w][(wave * 16 + l16) * 40 + quad * 8];
        #pragma unroll
        for (int t = 0; t < 4; t++) {
            short8 bf = *(const short8*)&Bt_lds[(t * 16 + l16) * 40 + quad * 8];
            #pragma unroll
            for (int w = 0; w < 3; w++)
                acc[w][t] = __builtin_amdgcn_mfma_f32_16x16x32_bf16(af[w], bf, acc[w][t], 0, 0, 0);
        }
    }

    float biasv[3][4];
    const void* Bs[3] = {bk, bv, bp};
    #pragma unroll
    for (int w = 0; w < 3; w++)
        #pragma unroll
        for (int r = 0; r < 4; r++)
            biasv[w][r] = loadS(Bs[w], (size_t)(o0 + wave * 16 + quad * 4 + r), isbf);

    // ---- K epilogue: T[n][o], store [bl][n][C] ----
    __syncthreads();
    #pragma unroll
    for (int t = 0; t < 4; t++)
        #pragma unroll
        for (int r = 0; r < 4; r++)
            T_lds[(t * 16 + l16) * 72 + wave * 16 + quad * 4 + r] =
                f2bf(acc[0][t][r] + biasv[0][r]);
    __syncthreads();
    for (int u = tid; u < 512; u += 256) {
        int n = u >> 3, o8 = (u & 7) * 8;
        *(short8*)&k_ws[((size_t)bl * NN + n0 + n) * CC + o0 + o8] =
            *(const short8*)&T_lds[n * 72 + o8];
    }

    // ---- V epilogue: T[o][n], store [bl][C][n] ----
    __syncthreads();
    #pragma unroll
    for (int t = 0; t < 4; t++)
        #pragma unroll
        for (int r = 0; r < 4; r++)
            T_lds[(wave * 16 + quad * 4 + r) * 72 + t * 16 + l16] =
                f2bf(acc[1][t][r] + biasv[1][r]);
    __syncthreads();
    for (int u = tid; u < 512; u += 256) {
        int o = u >> 3, n8 = (u & 7) * 8;
        *(short8*)&v_ws[((size_t)bl * CC + o0 + o) * NN + n0 + n8] =
            *(const short8*)&T_lds[o * 72 + n8];
    }

    // ---- P epilogue: direct fp32 stores ----
    #pragma unroll
    for (int t = 0; t < 4; t++)
        #pragma unroll
        for (int r = 0; r < 4; r++)
            out[((size_t)b * CC + o0 + wave * 16 + quad * 4 + r) * NN +
                n0 + t * 16 + l16] = acc[2][t][r] + biasv[2][r];
}

// -------------------------------------------------------------------------
// attn_mfma v7 = v5 (369us proven) + counted-vmcnt double-buffered pipeline:
// K dbuf [2][32][256], V single [256][32], P [4][16][40] = 54272 B
// (<= 59392 -> 2 blocks/CU). Per iter: wait vmcnt(8) (K it, issued 2 iters
// ago) -> barrier -> QK/softmax -> wait vmcnt(4) (V it, issued 1 iter ago)
// -> barrier -> PV -> barrier -> issue V(it+1), K(it+2). No vmcnt(0) drain
// in the loop. grid (NN/64, BC), block 256 (4 waves).
// -------------------------------------------------------------------------
__global__ __launch_bounds__(256, 2) void attn_mfma(
    const void* __restrict__ x,
    const void* __restrict__ Wq, const void* __restrict__ bq,
    const ushort* __restrict__ k_ws, const ushort* __restrict__ v_ws,
    float* __restrict__ out, int b0)
{
    // Pool: 29696 ushorts = 59392 B  (proven 2 blocks/CU)
    __shared__ __align__(16) ushort lds[29696];
    // Flash phase:
    ushort* K0_lds = lds;            // [32][256] swizzled: slot p holds p^(row&7)
    ushort* K1_lds = lds + 8192;     // second K buffer
    ushort* Vt_lds = lds + 16384;    // [256][32] linear
    ushort* P_lds  = lds + 24576;    // [4][16][40] wave-local
    // Phase A aliases:
    ushort* Qt_lds = lds;            // [64][264]
    ushort* Wc_lds = lds + 16896;    // [256][40]
    ushort* Xt_lds = lds + 27136;    // [64][40]
    float*  Tf     = (float*)lds;    // [128][68] fp32 epilogue

    const bool isbf = detect_bf16(x);
    const int tid  = threadIdx.x;
    const int wave = tid >> 6;
    const int lane = tid & 63;
    const int l16  = lane & 15;
    const int quad = lane >> 4;
    const int bl = blockIdx.y;
    const int b  = b0 + bl;
    const int n0 = blockIdx.x * 64;

    floatx4 zero4 = {0.f, 0.f, 0.f, 0.f};

    // ---- Phase A: Q = (x^T Wq^T + bq) * C^-0.5, D[n][o] ----
    {
        floatx4 qacc[16];
        #pragma unroll
        for (int t = 0; t < 16; t++) qacc[t] = zero4;

        for (int k0 = 0; k0 < CC; k0 += 32) {
            __syncthreads();
            #pragma unroll
            for (int i = 0; i < 4; i++) {
                int u = tid + i * 256;
                int row = u >> 2, c8 = (u & 3) * 8;
                *(short8*)&Wc_lds[row * 40 + c8] =
                    load8(Wq, (size_t)row * CC + k0 + c8, isbf);
            }
            {
                int c = tid >> 3, n8 = (tid & 7) * 8;
                short8 xv = load8(x, ((size_t)b * CC + k0 + c) * NN + n0 + n8, isbf);
                #pragma unroll
                for (int j = 0; j < 8; j++)
                    Xt_lds[(n8 + j) * 40 + c] = ((ushort*)&xv)[j];
            }
            __syncthreads();

            short8 af = *(const short8*)&Xt_lds[(wave * 16 + l16) * 40 + quad * 8];
            #pragma unroll
            for (int ct = 0; ct < 16; ct++) {
                short8 bf = *(const short8*)&Wc_lds[(ct * 16 + l16) * 40 + quad * 8];
                qacc[ct] = __builtin_amdgcn_mfma_f32_16x16x32_bf16(af, bf, qacc[ct], 0, 0, 0);
            }
        }

        __syncthreads();
        #pragma unroll
        for (int ct = 0; ct < 16; ct++) {
            float bqv = loadS(bq, (size_t)(ct * 16 + l16), isbf);
            #pragma unroll
            for (int r = 0; r < 4; r++)
                Qt_lds[(wave * 16 + quad * 4 + r) * 264 + ct * 16 + l16] =
                    f2bf((qacc[ct][r] + bqv) * 0.0625f);
        }
    }
    __syncthreads();   // Qt ushort writes -> short8 reads
    short8 qf[8];
    #pragma unroll
    for (int s = 0; s < 8; s++)
        qf[s] = *(const short8*)&Qt_lds[(wave * 16 + l16) * 264 + s * 32 + quad * 8];
    __syncthreads();   // all waves done with Qt before staging overwrites it

    // ---- Phase B: flash attention, KVBLK=32, pipelined gll staging ----
    const ushort* kp = k_ws + (size_t)bl * NN * CC;   // [n][C]
    const ushort* vp = v_ws + (size_t)bl * CC * NN;   // [C][n]

    floatx4 Oacc[16];
    #pragma unroll
    for (int t = 0; t < 16; t++) Oacc[t] = zero4;
    float mrow[4], lrow[4];
    #pragma unroll
    for (int r = 0; r < 4; r++) { mrow[r] = -1e30f; lrow[r] = 0.f; }

    const int NT = NN / 32;   // 128

    // staging: 4 gll16 each; K source pre-swizzled (slot sw holds sw^(row&7))
    auto stageK = [&](int it, ushort* kb) {
        int m0 = it * 32;
        #pragma unroll
        for (int i = 0; i < 4; i++) {
            int c = wave * 4 + i;
            int row = c * 2 + (lane >> 5);
            int sw  = (lane & 31) ^ (row & 7);
            gll16(kp + (size_t)(m0 + row) * CC + sw * 8, kb + c * 512);
        }
    };
    auto stageV = [&](int it) {
        int m0 = it * 32;
        #pragma unroll
        for (int i = 0; i < 4; i++) {
            int c = wave * 4 + i;
            int ch = c * 16 + (lane >> 2);
            gll16(vp + (size_t)ch * NN + m0 + (lane & 3) * 8, Vt_lds + c * 512);
        }
    };

    // prologue: K(0), V(0), K(1)  (order matters for vmcnt ledger)
    stageK(0, K0_lds);
    stageV(0);
    stageK(1, K1_lds);

    #pragma unroll 1
    for (int it = 0; it < NT; ++it) {
        ushort* Kc = (it & 1) ? K1_lds : K0_lds;

        // K(it) done: it's the 3rd-newest 4-group in steady state
        if (it + 1 < NT) asm volatile("s_waitcnt vmcnt(8)" ::: "memory");
        else             asm volatile("s_waitcnt vmcnt(4)" ::: "memory");
        __builtin_amdgcn_s_barrier();    // K(it) visible block-wide

        // QK^T: S[t] = Q . K(16 keys of t), k=256 over 8 slices
        floatx4 S[2];
        S[0] = zero4; S[1] = zero4;
        #pragma unroll
        for (int t = 0; t < 2; t++) {
            int row = t * 16 + l16;
            int rsw = row & 7;
            #pragma unroll
            for (int s = 0; s < 8; s++) {
                short8 kf = *(const short8*)&Kc[row * 256 + ((s * 4 + quad) ^ rsw) * 8];
                S[t] = __builtin_amdgcn_mfma_f32_16x16x32_bf16(qf[s], kf, S[t], 0, 0, 0);
            }
        }

        // online softmax: rows = quad*4+r, keys = (t*16+l16)
        float alpha[4];
        #pragma unroll
        for (int r = 0; r < 4; r++) {
            float mx = fmaxf(S[0][r], S[1][r]);
            mx = fmaxf(mx, __shfl_xor(mx, 1, 64));
            mx = fmaxf(mx, __shfl_xor(mx, 2, 64));
            mx = fmaxf(mx, __shfl_xor(mx, 4, 64));
            mx = fmaxf(mx, __shfl_xor(mx, 8, 64));
            float mn = fmaxf(mrow[r], mx);
            float al = __expf(mrow[r] - mn);
            mrow[r] = mn;
            float p0 = __expf(S[0][r] - mn);
            float p1 = __expf(S[1][r] - mn);
            S[0][r] = p0; S[1][r] = p1;
            float rs = p0 + p1;
            rs += __shfl_xor(rs, 1, 64);
            rs += __shfl_xor(rs, 2, 64);
            rs += __shfl_xor(rs, 4, 64);
            rs += __shfl_xor(rs, 8, 64);
            lrow[r] = lrow[r] * al + rs;
            alpha[r] = al;
        }

        // write P (wave-local rows; only this wave reads them back)
        #pragma unroll
        for (int r = 0; r < 4; r++) {
            int row = wave * 640 + (quad * 4 + r) * 40;
            P_lds[row + l16]      = f2bf(S[0][r]);
            P_lds[row + 16 + l16] = f2bf(S[1][r]);
        }

        // rescale O while P writes drain (VALU overlaps DS pipe)
        #pragma unroll
        for (int ct = 0; ct < 16; ct++)
            #pragma unroll
            for (int r = 0; r < 4; r++)
                Oacc[ct][r] *= alpha[r];

        // own QK reads + P writes done; then V(it) landed (own)
        asm volatile("s_waitcnt lgkmcnt(0)" ::: "memory");
        __builtin_amdgcn_sched_barrier(0);
        if (it + 1 < NT) asm volatile("s_waitcnt vmcnt(4)" ::: "memory");
        else             asm volatile("s_waitcnt vmcnt(0)" ::: "memory");
        __builtin_amdgcn_s_barrier();    // V(it) visible; all waves done with Kc

        // PV: O[ct] += P . V(16 ch of ct), one MFMA per ct (k=32)
        short8 pf = *(const short8*)&P_lds[wave * 640 + l16 * 40 + quad * 8];
        #pragma unroll
        for (int ct = 0; ct < 16; ct++) {
            int ch = ct * 16 + l16;
            short8 vf = *(const short8*)&Vt_lds[ch * 32 + quad * 8];
            Oacc[ct] = __builtin_amdgcn_mfma_f32_16x16x32_bf16(pf, vf, Oacc[ct], 0, 0, 0);
        }

        // own PV reads done -> barrier -> safe to overwrite V and Kc
        asm volatile("s_waitcnt lgkmcnt(0)" ::: "memory");
        __builtin_amdgcn_sched_barrier(0);
        __builtin_amdgcn_s_barrier();

        if (it + 1 < NT) stageV(it + 1);
        if (it + 2 < NT) stageK(it + 2, Kc);
    }

    // ---- epilogue: out = h/l + P (fp32 RMW), two 128-channel halves ----
    float linv[4];
    #pragma unroll
    for (int r = 0; r < 4; r++) linv[r] = 1.0f / lrow[r];

    #pragma unroll
    for (int h = 0; h < 2; h++) {
        __syncthreads();   // flash LDS dead (or prev half consumed)
        #pragma unroll
        for (int ct = h * 8; ct < h * 8 + 8; ct++)
            #pragma unroll
            for (int r = 0; r < 4; r++)
                Tf[(ct * 16 + l16 - h * 128) * 68 + wave * 16 + quad * 4 + r] =
                    Oacc[ct][r] * linv[r];
        __syncthreads();
        #pragma unroll
        for (int i = 0; i < 8; i++) {
            int u = tid + i * 256;           // 2048 float4 slots = 128ch x 16
            int row = u >> 4, col4 = (u & 15) * 4;
            size_t gi = ((size_t)b * CC + h * 128 + row) * NN + n0 + col4;
            floatx4 pv = *(const floatx4*)&out[gi];
            floatx4 tv = *(const floatx4*)&Tf[row * 68 + col4];
            pv[0] += tv[0]; pv[1] += tv[1]; pv[2] += tv[2]; pv[3] += tv[3];
            *(floatx4*)&out[gi] = pv;
        }
    }
}

// -------------------------------------------------------------------------
extern "C" void kernel_launch(void* const* d_in, const int* in_sizes, int n_in,
                              void* d_out, int out_size, void* d_ws, size_t ws_size,
                              hipStream_t stream) {
    int xi = 0;
    for (int i = 0; i < n_in; i++)
        if (in_sizes[i] == NB * CC * NN) xi = i;

    const void *x, *Wq, *bq, *Wk, *bk, *Wv, *bv, *Wp, *bp;
    if (xi == 0) {
        x  = d_in[0];
        Wq = d_in[1]; bq = d_in[2];
        Wk = d_in[3]; bk = d_in[4];
        Wv = d_in[5]; bv = d_in[6];
        Wp = d_in[7]; bp = d_in[8];
    } else {
        int wi[4], bi[4], nw = 0, nb = 0;
        for (int i = 0; i < n_in; i++) {
            if (i == xi) continue;
            if (in_sizes[i] == CC * CC) { if (nw < 4) wi[nw++] = i; }
            else                        { if (nb < 4) bi[nb++] = i; }
        }
        x  = d_in[xi];
        Wk = d_in[wi[0]]; Wp = d_in[wi[1]]; Wq = d_in[wi[2]]; Wv = d_in[wi[3]];
        bk = d_in[bi[0]]; bp = d_in[bi[1]]; bq = d_in[bi[2]]; bv = d_in[bi[3]];
    }

    float*  out = (float*)d_out;     // fp32 output
    ushort* ws  = (ushort*)d_ws;

    const size_t tsz_b = (size_t)NN * CC;
    int BC = 8;
    while (BC > 1 && (size_t)BC * tsz_b * 2 * 2 > ws_size) BC >>= 1;
    ushort* k_ws = ws;
    ushort* v_ws = ws + (size_t)BC * tsz_b;

    for (int c0 = 0; c0 < NB; c0 += BC) {
        projkvp<<<dim3(NN / 64, CC / 64, BC), dim3(256), 0, stream>>>(
            x, Wk, bk, Wv, bv, Wp, bp, k_ws, v_ws, out, c0);
        attn_mfma<<<dim3(NN / 64, BC), dim3(256), 0, stream>>>(
            x, Wq, bq, k_ws, v_ws, out, c0);
    }
}